// Round 16
// baseline (136.403 us; speedup 1.0000x reference)
//
#include <hip/hip_runtime.h>
#include <hip/hip_bf16.h>
#include <stdint.h>

#define S_LEN 2048
#define EMB   1536
#define NH    12
#define HD    128
#define N3    4608
#define RMS_EPS 1e-5f
#define ATTN_SCALE 0.08838834764831845f  // 1/sqrt(128)
#define SPLIT 2
#define LOG2E 1.44269504088896f
#define DEFER_THR 11.5416f   // 8 * log2(e)

typedef short short8_t __attribute__((ext_vector_type(8)));
typedef float f32x4    __attribute__((ext_vector_type(4)));

typedef __attribute__((address_space(1))) const void g1_void;
typedef __attribute__((address_space(3))) void l3_void;

__device__ __forceinline__ void gload_lds16(const void* g, void* l) {
  __builtin_amdgcn_global_load_lds((g1_void*)g, (l3_void*)l, 16, 0, 0);
}

__device__ __forceinline__ short f2bf(float f) {
  union { float f; unsigned u; } v; v.f = f;
  unsigned r = (v.u + 0x7FFFu + ((v.u >> 16) & 1u)) >> 16;
  return (short)(r & 0xFFFFu);
}
__device__ __forceinline__ float bf2f(short s) {
  union { unsigned u; float f; } v; v.u = ((unsigned)(unsigned short)s) << 16;
  return v.f;
}

// ---------------- fp32 -> bf16 elementwise ----------------
__global__ __launch_bounds__(256) void k_cvt_bf16(const float* __restrict__ in,
                                                  short* __restrict__ out, int n) {
  int i = (blockIdx.x * 256 + threadIdx.x) * 4;
  if (i + 3 < n) {
    float4 v = *(const float4*)(in + i);
    short4 o;
    o.x = f2bf(v.x); o.y = f2bf(v.y); o.z = f2bf(v.z); o.w = f2bf(v.w);
    *(short4*)(out + i) = o;
  }
}

// ---------------- (K,N) fp32 -> (N,K) bf16 transpose ----------------
__global__ __launch_bounds__(256) void k_transpose_cvt(const float* __restrict__ W,
                                                       short* __restrict__ Wt,
                                                       int K, int N) {
  __shared__ float t[32][33];
  int n0 = blockIdx.x * 32, k0 = blockIdx.y * 32;
  int tx = threadIdx.x, ty = threadIdx.y;  // block (32,8)
#pragma unroll
  for (int r = 0; r < 4; ++r) {
    int k = ty + r * 8;
    t[k][tx] = W[(size_t)(k0 + k) * N + n0 + tx];
  }
  __syncthreads();
#pragma unroll
  for (int r = 0; r < 4; ++r) {
    int j = ty + r * 8;
    Wt[(size_t)(n0 + j) * K + k0 + tx] = f2bf(t[tx][j]);
  }
}

// ---------------- bf16 GEMM v8 (QKV): split-K=2, 128x128 tile, BK=64,
// SINGLE 32KB buffer (v3 structure, 5 blocks/CU cap). Grid (nbn, nbm, 2):
// z-half computes K in [z*K/2, (z+1)*K/2) -> bf16 partial C0/C1.
// 1152 blocks = 4.5 blocks/CU resident: cross-block overlap hides drains. ----------------
__global__ __launch_bounds__(256, 4) void k_gemm_v8(const short* __restrict__ A,
                                                    const short* __restrict__ Bt,
                                                    const float* __restrict__ bias,
                                                    short* __restrict__ C0,
                                                    short* __restrict__ C1,
                                                    int M, int N, int K) {
  __shared__ short lds[2][128 * 64];   // [A/B][row*64 + k], 32 KiB total
  const int tid = threadIdx.x;
  const int lane = tid & 63, wid = tid >> 6;
  const int wr = (wid >> 1) * 64, wc = (wid & 1) * 64;
  const int bn = blockIdx.x * 128, bm = blockIdx.y * 128;
  const int z = blockIdx.z;
  const int lr = lane & 15, lg = lane >> 4;
  const int swz = (lr & 7) << 4;

  const int srow = lane >> 3;                  // row within 8-row segment
  const int skc  = ((lane & 7) ^ srow) * 8;    // pre-swizzled global k offset

  f32x4 acc[4][4] = {};
  const int kh = K >> 1;           // half-K
  const int k0 = z * kh;
  const int nk = kh >> 6;          // K-steps in this half

  for (int t = 0; t < nk; ++t) {
    const int kt = k0 + (t << 6);
    __syncthreads();   // everyone done reading lds from prev iter
#pragma unroll
    for (int it = 0; it < 4; ++it) {
      int seg = wid * 4 + it;
      int row = seg * 8 + srow;
      gload_lds16(A  + (size_t)(bm + row) * K + kt + skc, &lds[0][seg * 512]);
      gload_lds16(Bt + (size_t)(bn + row) * K + kt + skc, &lds[1][seg * 512]);
    }
    __syncthreads();   // drains vmcnt(0): tile staged & visible
    const char* baseA = (const char*)&lds[0][0];
    const char* baseB = (const char*)&lds[1][0];
#pragma unroll
    for (int kk = 0; kk < 2; ++kk) {
      short8_t af[4], bfr[4];
#pragma unroll
      for (int m = 0; m < 4; ++m) {
        int row = wr + m * 16 + lr;
        af[m] = *(const short8_t*)(baseA + ((row * 128 + kk * 64 + lg * 16) ^ swz));
      }
#pragma unroll
      for (int n = 0; n < 4; ++n) {
        int row = wc + n * 16 + lr;
        bfr[n] = *(const short8_t*)(baseB + ((row * 128 + kk * 64 + lg * 16) ^ swz));
      }
#pragma unroll
      for (int m = 0; m < 4; ++m)
#pragma unroll
        for (int n = 0; n < 4; ++n)
          acc[m][n] = __builtin_amdgcn_mfma_f32_16x16x32_bf16(af[m], bfr[n], acc[m][n], 0, 0, 0);
    }
  }

  short* C = z ? C1 : C0;
#pragma unroll
  for (int m = 0; m < 4; ++m)
#pragma unroll
    for (int n = 0; n < 4; ++n) {
      int col = bn + wc + n * 16 + lr;
      float bv = z ? 0.f : bias[col];   // bias once (half 0); k_post sums halves
#pragma unroll
      for (int r = 0; r < 4; ++r) {
        int row = bm + wr + m * 16 + lg * 4 + r;
        C[(size_t)row * N + col] = f2bf(acc[m][n][r] + bv);
      }
    }
}

// ---------------- bf16 GEMM v7 (proj): v6b schedule + XCD-cohort partition ----------------
template<bool OBF>
__global__ __launch_bounds__(256, 2) void k_gemm_v7(const short* __restrict__ A,
                                                    const short* __restrict__ Bt,
                                                    const float* __restrict__ bias,
                                                    void* __restrict__ Cv,
                                                    int M, int N, int K) {
  __shared__ short lds[2][2][128 * 64];   // [buf][A/B][row*64+k], 64 KiB
  const int tid = threadIdx.x;
  const int lane = tid & 63, wid = tid >> 6;
  const int wr = (wid >> 1) * 64, wc = (wid & 1) * 64;

  const int nbn = N >> 7;
  const int perbn = nbn >> 2;
  const int x = blockIdx.x & 7;
  const int s = blockIdx.x >> 3;
  const int bm = ((x >> 2) * 8 + (s & 7)) * 128;
  const int bn = ((x & 3) * perbn + (s >> 3)) * 128;

  const int lr = lane & 15, lg = lane >> 4;
  const int swz = (lr & 7) << 4;
  const int srow = lane >> 3;
  const int skc  = ((lane & 7) ^ srow) * 8;

  f32x4 acc[4][4] = {};
  const int nk = K >> 6;

#define GSTAGE(kt_, buf_)                                                          \
  {                                                                                \
    const int kt__ = (kt_);                                                        \
    _Pragma("unroll")                                                              \
    for (int it = 0; it < 4; ++it) {                                               \
      int seg = wid * 4 + it;                                                      \
      int row = seg * 8 + srow;                                                    \
      gload_lds16(A  + (size_t)(bm + row) * K + kt__ + skc, &lds[buf_][0][seg * 512]); \
      gload_lds16(Bt + (size_t)(bn + row) * K + kt__ + skc, &lds[buf_][1][seg * 512]); \
    }                                                                              \
  }

  GSTAGE(0, 0);
  if (nk > 1) {
    GSTAGE(64, 1);
    asm volatile("s_waitcnt vmcnt(8)" ::: "memory");
  } else {
    asm volatile("s_waitcnt vmcnt(0)" ::: "memory");
  }
  __builtin_amdgcn_s_barrier();

  int cur = 0;
  for (int t = 0; t < nk; ++t) {
    const char* baseA = (const char*)&lds[cur][0][0];
    const char* baseB = (const char*)&lds[cur][1][0];

    short8_t af0[4], bf0[4], af1[4], bf1[4];
#pragma unroll
    for (int m = 0; m < 4; ++m) {
      int rowA = wr + m * 16 + lr;
      int rowB = wc + m * 16 + lr;
      af0[m] = *(const short8_t*)(baseA + ((rowA * 128 + 0 * 64 + lg * 16) ^ swz));
      bf0[m] = *(const short8_t*)(baseB + ((rowB * 128 + 0 * 64 + lg * 16) ^ swz));
      af1[m] = *(const short8_t*)(baseA + ((rowA * 128 + 1 * 64 + lg * 16) ^ swz));
      bf1[m] = *(const short8_t*)(baseB + ((rowB * 128 + 1 * 64 + lg * 16) ^ swz));
    }

    __builtin_amdgcn_s_setprio(1);
#pragma unroll
    for (int m = 0; m < 4; ++m)
#pragma unroll
      for (int n = 0; n < 4; ++n)
        acc[m][n] = __builtin_amdgcn_mfma_f32_16x16x32_bf16(af0[m], bf0[n], acc[m][n], 0, 0, 0);
    __builtin_amdgcn_s_setprio(0);

    // rule-#18 fence: sched_barrier(0) right after inline-asm lgkmcnt(0)
    asm volatile("s_waitcnt lgkmcnt(0)" ::: "memory");
    __builtin_amdgcn_sched_barrier(0);
    __builtin_amdgcn_s_barrier();

    if (t + 2 < nk) GSTAGE((t + 2) << 6, cur);

    __builtin_amdgcn_s_setprio(1);
#pragma unroll
    for (int m = 0; m < 4; ++m)
#pragma unroll
      for (int n = 0; n < 4; ++n)
        acc[m][n] = __builtin_amdgcn_mfma_f32_16x16x32_bf16(af1[m], bf1[n], acc[m][n], 0, 0, 0);
    __builtin_amdgcn_s_setprio(0);

    if (t + 2 < nk) {
      asm volatile("s_waitcnt vmcnt(8)" ::: "memory");
    } else {
      asm volatile("s_waitcnt vmcnt(0)" ::: "memory");
    }
    __builtin_amdgcn_s_barrier();
    cur ^= 1;
  }
#undef GSTAGE

#pragma unroll
  for (int m = 0; m < 4; ++m)
#pragma unroll
    for (int n = 0; n < 4; ++n) {
      int col = bn + wc + n * 16 + lr;
      float bv = bias[col];
#pragma unroll
      for (int r = 0; r < 4; ++r) {
        int row = bm + wr + m * 16 + lg * 4 + r;
        float v = acc[m][n][r] + bv;
        if (OBF) ((short*)Cv)[(size_t)row * N + col] = f2bf(v);
        else     ((float*)Cv)[(size_t)row * N + col] = v;
      }
    }
}

// ---------------- fused RMSNorm + RoPE (q,k) + V transpose; sums split-K halves;
// q pre-scaled by SC2 ----------------
__global__ __launch_bounds__(256) void k_post(const short* __restrict__ qkvA,
                                              const short* __restrict__ qkvB,
                                              const float* __restrict__ cosv,
                                              const float* __restrict__ sinv,
                                              const float* __restrict__ qw,
                                              const float* __restrict__ kw,
                                              short* __restrict__ qbo,
                                              short* __restrict__ kbo,
                                              short* __restrict__ vt) {
  __shared__ short ldsv[64 * 130];
  const int h = blockIdx.x, s0 = blockIdx.y * 64;
  const int t = threadIdx.x;
  const int r = t >> 2, j = t & 3;
  const int s = s0 + r;
  const size_t rowbase = (size_t)s * N3 + h * HD;
  const float SC2 = ATTN_SCALE * LOG2E;

  {
    const short* va = qkvA + rowbase + 2 * EMB + j * 32;
    const short* vb = qkvB + rowbase + 2 * EMB + j * 32;
#pragma unroll
    for (int i4 = 0; i4 < 4; ++i4) {
      short8_t xa = *(const short8_t*)(va + i4 * 8);
      short8_t xb = *(const short8_t*)(vb + i4 * 8);
      short8_t o8;
#pragma unroll
      for (int e = 0; e < 8; ++e) o8[e] = f2bf(bf2f(xa[e]) + bf2f(xb[e]));
      *(short8_t*)&ldsv[r * 130 + j * 32 + i4 * 8] = o8;
    }
  }

#pragma unroll
  for (int qk = 0; qk < 2; ++qk) {
    const short* pa = qkvA + rowbase + qk * EMB + j * 32;
    const short* pb = qkvB + rowbase + qk * EMB + j * 32;
    const float* w = qk ? kw : qw;
    float v[32];
#pragma unroll
    for (int i4 = 0; i4 < 4; ++i4) {
      short8_t xa = *(const short8_t*)(pa + i4 * 8);
      short8_t xb = *(const short8_t*)(pb + i4 * 8);
#pragma unroll
      for (int e = 0; e < 8; ++e) v[i4 * 8 + e] = bf2f(xa[e]) + bf2f(xb[e]);
    }
    float ss = 0.f;
#pragma unroll
    for (int i = 0; i < 32; ++i) ss += v[i] * v[i];
    ss += __shfl_xor(ss, 1);
    ss += __shfl_xor(ss, 2);
    float rsq = rsqrtf(ss * (1.0f / HD) + RMS_EPS);
    if (qk == 0) rsq *= SC2;   // bake attention scale + log2e into q
#pragma unroll
    for (int i = 0; i < 32; ++i) v[i] = v[i] * rsq * w[j * 32 + i];
    const float* cp = cosv + (size_t)s * 64 + (j & 1) * 32;
    const float* sp = sinv + (size_t)s * 64 + (j & 1) * 32;
    short out[32];
#pragma unroll
    for (int i = 0; i < 32; ++i) {
      float part = __shfl_xor(v[i], 2);
      float c = cp[i], sn = sp[i];
      float o = (j < 2) ? (v[i] * c - part * sn) : (v[i] * c + part * sn);
      out[i] = f2bf(o);
    }
    short* dst = (qk ? kbo : qbo) + ((size_t)h * S_LEN + s) * HD + j * 32;
#pragma unroll
    for (int i4 = 0; i4 < 4; ++i4) {
      short8_t o8;
#pragma unroll
      for (int e = 0; e < 8; ++e) o8[e] = out[i4 * 8 + e];
      *(short8_t*)(dst + i4 * 8) = o8;
    }
  }

  __syncthreads();
  const int sl = t & 63, wv = t >> 6;
#pragma unroll
  for (int it = 0; it < 32; ++it) {
    int d = it * 4 + wv;
    vt[((size_t)h * HD + d) * S_LEN + s0 + sl] = ldsv[sl * 130 + d];
  }
}

// ---------------- flash attention v6: K half-tile layout (128B rows), pre-scaled Q ----------------
__global__ __launch_bounds__(512, 2) void k_attn(const short* __restrict__ qb,
                                                 const short* __restrict__ kb,
                                                 const short* __restrict__ vt,
                                                 const int* __restrict__ cu, int nseg,
                                                 short* __restrict__ Opart,
                                                 float* __restrict__ mlpart) {
  __shared__ short ldsK[2][8192];       // [buf][half(2) x 64 key-rows x 64 d] 128B rows, swizzled
  __shared__ short ldsV[2][128 * 64];   // [buf][d row 128B], swizzled
  __shared__ short ldsP[8 * 16 * 64];   // per-wave 2KB, [q][key] swizzled

  const int wg = blockIdx.x;
  const int member = wg / 48;
  const int c = wg % 48;
  const int p = c & 1;
  const int h = c >> 2;
  const int qt = ((c >> 1) & 1) * 8 + member;

  const int q0 = qt * 128;
  const int tid = threadIdx.x, l = tid & 63, w = tid >> 6;
  const int lr = l & 15, lg = l >> 4;

  const short* kb_h = kb + (size_t)h * S_LEN * HD;
  const short* vt_h = vt + (size_t)h * HD * S_LEN;

  const int qrow_sm = q0 + w * 16 + lr;
  int segq = 0;
  for (int i = 1; i <= nseg; ++i) if (qrow_sm >= cu[i]) segq = i;
  const int rs_s = (segq == 0) ? 0 : cu[segq];
  const int re_s = (segq < nseg) ? cu[segq + 1] : S_LEN;
  float m = -INFINITY, lsum = 0.f;

  int seg0 = 0, seg1 = 0;
  for (int i = 1; i <= nseg; ++i) {
    if (q0 >= cu[i]) seg0 = i;
    if (q0 + 127 >= cu[i]) seg1 = i;
  }
  const int ks = (seg0 == 0) ? 0 : cu[seg0];
  const int ke = (seg1 < nseg) ? cu[seg1 + 1] : S_LEN;
  const int kt0 = (ks >> 6) << 6;
  const int nt = (ke - kt0 + 63) >> 6;
  const int tpb = (nt + SPLIT - 1) / SPLIT;
  const int tb0 = p * tpb;
  const int tb1 = (tb0 + tpb < nt) ? tb0 + tpb : nt;

  const int vseg_row = l >> 3;

  short8_t qf[4];
  {
    int srow = q0 + w * 16 + lr;
    const short* qp = qb + ((size_t)h * S_LEN + srow) * HD;
#pragma unroll
    for (int kk = 0; kk < 4; ++kk)
      qf[kk] = *(const short8_t*)(qp + kk * 32 + lg * 8);
  }

  f32x4 cacc[8] = {};

#define STAGE(kt_, buf_)                                                          \
  {                                                                               \
    const int kt__ = (kt_);                                                       \
    _Pragma("unroll")                                                             \
    for (int it = 0; it < 2; ++it) {                                              \
      int s = w * 2 + it;                                                         \
      int half = s >> 3;                                                          \
      int krow = (s & 7) * 8 + (l >> 3);                                          \
      int kc = half * 64 + (((l & 7) ^ (l >> 3)) * 8);                            \
      gload_lds16(kb_h + (size_t)(kt__ + krow) * HD + kc, &ldsK[buf_][s * 512]);  \
      int drow = s * 8 + vseg_row;                                                \
      int sv = ((l & 7) ^ (drow & 7)) * 8;                                        \
      gload_lds16(vt_h + (size_t)drow * S_LEN + kt__ + sv, &ldsV[buf_][s * 512]); \
    }                                                                             \
  }

  if (tb0 < tb1)     STAGE(kt0 + tb0 * 64, 0);
  if (tb0 + 1 < tb1) {
    STAGE(kt0 + (tb0 + 1) * 64, 1);
    asm volatile("s_waitcnt vmcnt(4)" ::: "memory");
  } else {
    asm volatile("s_waitcnt vmcnt(0)" ::: "memory");
  }
  __builtin_amdgcn_s_barrier();

  int cur = 0;
  for (int ti = tb0; ti < tb1; ++ti) {
    const int kt = kt0 + ti * 64;
    const char* bK = (const char*)&ldsK[cur][0];
    const char* bV = (const char*)&ldsV[cur][0];

    f32x4 sacc[4] = {};
    __builtin_amdgcn_s_setprio(1);
#pragma unroll
    for (int n = 0; n < 4; ++n) {
#pragma unroll
      for (int kk = 0; kk < 4; ++kk) {
        int row = n * 16 + lr;
        int byte = (kk >> 1) * 8192 + row * 128 + (kk & 1) * 64 + lg * 16;
        byte ^= (lr & 7) << 4;
        short8_t kf = *(const short8_t*)(bK + byte);
        sacc[n] = __builtin_amdgcn_mfma_f32_16x16x32_bf16(kf, qf[kk], sacc[n], 0, 0, 0);
      }
    }
    __builtin_amdgcn_s_setprio(0);

    if (!__all((kt >= rs_s) && (kt + 64 <= re_s))) {
#pragma unroll
      for (int n = 0; n < 4; ++n) {
        int kbase = kt + n * 16 + lg * 4;
#pragma unroll
        for (int r = 0; r < 4; ++r) {
          int key = kbase + r;
          sacc[n][r] = (key >= rs_s && key < re_s) ? sacc[n][r] : -1e30f;
        }
      }
    }

    float tm = sacc[0][0];
#pragma unroll
    for (int n = 0; n < 4; ++n)
#pragma unroll
      for (int r = 0; r < 4; ++r) tm = fmaxf(tm, sacc[n][r]);
    tm = fmaxf(tm, __shfl_xor(tm, 16));
    tm = fmaxf(tm, __shfl_xor(tm, 32));

    if (!__all(tm <= m + DEFER_THR)) {
      float mn = fmaxf(m, tm);
      float alpha = exp2f(m - mn);
      m = mn;
      lsum *= alpha;
      float a[4];
#pragma unroll
      for (int r = 0; r < 4; ++r) a[r] = __shfl(alpha, lg * 4 + r);
#pragma unroll
      for (int n = 0; n < 8; ++n)
#pragma unroll
        for (int r = 0; r < 4; ++r) cacc[n][r] *= a[r];
    }

    float ls = 0.f;
#pragma unroll
    for (int n = 0; n < 4; ++n) {
      short4 p4;
      float p0 = exp2f(sacc[n][0] - m);
      float p1 = exp2f(sacc[n][1] - m);
      float p2 = exp2f(sacc[n][2] - m);
      float p3 = exp2f(sacc[n][3] - m);
      ls += (p0 + p1) + (p2 + p3);
      p4.x = f2bf(p0); p4.y = f2bf(p1); p4.z = f2bf(p2); p4.w = f2bf(p3);
      int byte = lr * 128 + (n * 16 + lg * 4) * 2;
      byte ^= (lr & 7) << 4;
      *(short4*)((char*)ldsP + w * 2048 + byte) = p4;
    }
    ls += __shfl_xor(ls, 16);
    ls += __shfl_xor(ls, 32);
    lsum += ls;

    __builtin_amdgcn_s_setprio(1);
#pragma unroll
    for (int kk = 0; kk < 2; ++kk) {
      int byteP = lr * 128 + (kk * 32 + lg * 8) * 2;
      byteP ^= (lr & 7) << 4;
      short8_t pf = *(const short8_t*)((const char*)ldsP + w * 2048 + byteP);
#pragma unroll
      for (int n = 0; n < 8; ++n) {
        int d = n * 16 + lr;
        int byteV = d * 128 + (kk * 32 + lg * 8) * 2;
        byteV ^= (d & 7) << 4;
        short8_t vf = *(const short8_t*)(bV + byteV);
        cacc[n] = __builtin_amdgcn_mfma_f32_16x16x32_bf16(pf, vf, cacc[n], 0, 0, 0);
      }
    }
    __builtin_amdgcn_s_setprio(0);

    __builtin_amdgcn_s_barrier();
    if (ti + 2 < tb1) {
      STAGE(kt0 + (ti + 2) * 64, cur);
      asm volatile("s_waitcnt vmcnt(4)" ::: "memory");
    } else {
      asm volatile("s_waitcnt vmcnt(0)" ::: "memory");
    }
    __builtin_amdgcn_s_barrier();
    cur ^= 1;
  }
#undef STAGE

  const int b = (h * 16 + qt) * SPLIT + p;
#pragma unroll
  for (int r = 0; r < 4; ++r) {
    int qrow = w * 16 + lg * 4 + r;
#pragma unroll
    for (int n = 0; n < 8; ++n)
      Opart[(size_t)b * 16384 + qrow * 128 + n * 16 + lr] = f2bf(cacc[n][r]);
  }
  if (lg == 0) {
    mlpart[(size_t)b * 256 + w * 16 + lr] = m;
    mlpart[(size_t)b * 256 + 128 + w * 16 + lr] = lsum;
  }
}

// ---------------- combine split-K partials -> ctx bf16 (log2-domain m) ----------------
__global__ __launch_bounds__(512) void k_combine(const short* __restrict__ Opart,
                                                 const float* __restrict__ ml,
                                                 short* __restrict__ ctx) {
  const int h = blockIdx.x, qt = blockIdx.y, t = threadIdx.x;
  const int r = t >> 2, j = t & 3;   // r 0..127, j 0..3
  const int b0 = (h * 16 + qt) * SPLIT;

  float mp[SPLIT], lp[SPLIT], wp[SPLIT];
  float M = -INFINITY;
#pragma unroll
  for (int p = 0; p < SPLIT; ++p) {
    mp[p] = ml[(size_t)(b0 + p) * 256 + r];
    lp[p] = ml[(size_t)(b0 + p) * 256 + 128 + r];
    M = fmaxf(M, mp[p]);
  }
  float L = 0.f;
#pragma unroll
  for (int p = 0; p < SPLIT; ++p) {
    wp[p] = exp2f(mp[p] - M);
    L += lp[p] * wp[p];
  }
  const float inv = 1.0f / L;

  float acc[32];
#pragma unroll
  for (int i = 0; i < 32; ++i) acc[i] = 0.f;
#pragma unroll
  for (int p = 0; p < SPLIT; ++p) {
    const short* src = Opart + (size_t)(b0 + p) * 16384 + r * 128 + j * 32;
#pragma unroll
    for (int i4 = 0; i4 < 4; ++i4) {
      short8_t v = *(const short8_t*)(src + i4 * 8);
#pragma unroll
      for (int e = 0; e < 8; ++e) acc[i4 * 8 + e] += wp[p] * bf2f(v[e]);
    }
  }

  short* dst = ctx + (size_t)(qt * 128 + r) * EMB + h * HD + j * 32;
#pragma unroll
  for (int i4 = 0; i4 < 4; ++i4) {
    short8_t o8;
#pragma unroll
    for (int e = 0; e < 8; ++e) o8[e] = f2bf(acc[i4 * 8 + e] * inv);
    *(short8_t*)(dst + i4 * 8) = o8;
  }
}

extern "C" void kernel_launch(void* const* d_in, const int* in_sizes, int n_in,
                              void* d_out, int out_size, void* d_ws, size_t ws_size,
                              hipStream_t stream) {
  const float* x      = (const float*)d_in[0];
  const int*   cu     = (const int*)d_in[1];
  const float* cosv   = (const float*)d_in[2];
  const float* sinv   = (const float*)d_in[3];
  const float* w_qkv  = (const float*)d_in[4];
  const float* b_qkv  = (const float*)d_in[5];
  const float* q_norm = (const float*)d_in[6];
  const float* k_norm = (const float*)d_in[7];
  const float* w_proj = (const float*)d_in[8];
  const float* b_proj = (const float*)d_in[9];
  const int nseg = in_sizes[1] - 1;

  char* ws = (char*)d_ws;
  short* xb     = (short*)(ws);                    //  6,291,456 B (dead after QKV GEMM)
  short* wqkvT  = (short*)(ws + 6291456);          // 14,155,776 B
  short* wprojT = (short*)(ws + 20447232);         //  4,718,592 B
  short* qkvA   = (short*)(ws + 25165824);         // 18,874,368 B (dead after k_post)
  short* qb     = (short*)(ws + 44040192);         //  6,291,456 B
  short* kb     = (short*)(ws + 50331648);         //  6,291,456 B
  short* vt     = (short*)(ws + 56623104);         //  6,291,456 B
  short* ctxb   = (short*)(ws + 62914560);         //  6,291,456 B
  short* qkvB   = (short*)(ws + 69206016);         // 18,874,368 B (end 88,080,384)
  short* Opart  = qkvA;                            // reuse: 384*16384*2 = 12,582,912 B
  float* mlpart = (float*)ws;                      // reuse xb: 384*256*4 = 393,216 B

  k_cvt_bf16<<<(S_LEN * EMB) / 1024, 256, 0, stream>>>(x, xb, S_LEN * EMB);
  k_transpose_cvt<<<dim3(N3 / 32, EMB / 32), dim3(32, 8), 0, stream>>>(w_qkv, wqkvT, EMB, N3);
  k_transpose_cvt<<<dim3(EMB / 32, EMB / 32), dim3(32, 8), 0, stream>>>(w_proj, wprojT, EMB, EMB);
  k_gemm_v8<<<dim3(N3 / 128, S_LEN / 128, 2), 256, 0, stream>>>(xb, wqkvT, b_qkv, qkvA, qkvB, S_LEN, N3, EMB);
  k_post<<<dim3(NH, S_LEN / 64), 256, 0, stream>>>(qkvA, qkvB, cosv, sinv, q_norm, k_norm, qb, kb, vt);
  k_attn<<<dim3(NH * (S_LEN / 128) * SPLIT), 512, 0, stream>>>(qb, kb, vt, cu, nseg, Opart, mlpart);
  k_combine<<<dim3(NH, S_LEN / 128), 512, 0, stream>>>(Opart, mlpart, ctxb);
  k_gemm_v7<false><<<dim3((EMB / 128) * (S_LEN / 128)), 256, 0, stream>>>(ctxb, wprojT, b_proj, (float*)d_out, S_LEN, EMB, EMB);
}

// Round 17
// 133.411 us; speedup vs baseline: 1.0224x; 1.0224x over previous
//
#include <hip/hip_runtime.h>
#include <hip/hip_bf16.h>
#include <stdint.h>

#define S_LEN 2048
#define EMB   1536
#define NH    12
#define HD    128
#define N3    4608
#define RMS_EPS 1e-5f
#define ATTN_SCALE 0.08838834764831845f  // 1/sqrt(128)
#define SPLIT 3
#define LOG2E 1.44269504088896f
#define DEFER_THR 11.5416f   // 8 * log2(e)

typedef short short8_t __attribute__((ext_vector_type(8)));
typedef float f32x4    __attribute__((ext_vector_type(4)));

typedef __attribute__((address_space(1))) const void g1_void;
typedef __attribute__((address_space(3))) void l3_void;

__device__ __forceinline__ void gload_lds16(const void* g, void* l) {
  __builtin_amdgcn_global_load_lds((g1_void*)g, (l3_void*)l, 16, 0, 0);
}

__device__ __forceinline__ short f2bf(float f) {
  union { float f; unsigned u; } v; v.f = f;
  unsigned r = (v.u + 0x7FFFu + ((v.u >> 16) & 1u)) >> 16;
  return (short)(r & 0xFFFFu);
}
__device__ __forceinline__ float bf2f(short s) {
  union { unsigned u; float f; } v; v.u = ((unsigned)(unsigned short)s) << 16;
  return v.f;
}

// ---------------- merged prep: x->bf16 cvt + both weight transposes (1 dispatch) ----------------
// z ranges: [0,3072) cvt x; [3072,9984) transpose w_qkv; [9984,12288) transpose w_proj
__global__ __launch_bounds__(256) void k_prep(const float* __restrict__ x,
                                              const float* __restrict__ w_qkv,
                                              const float* __restrict__ w_proj,
                                              short* __restrict__ xb,
                                              short* __restrict__ wqkvT,
                                              short* __restrict__ wprojT) {
  const int z = blockIdx.x, tid = threadIdx.x;
  if (z < 3072) {
    int i = z * 1024 + tid * 4;
    float4 v = *(const float4*)(x + i);
    short4 o;
    o.x = f2bf(v.x); o.y = f2bf(v.y); o.z = f2bf(v.z); o.w = f2bf(v.w);
    *(short4*)(xb + i) = o;
    return;
  }
  __shared__ float t[32][33];
  const float* W; short* Wt; int K, N, n0, k0;
  if (z < 9984) {
    int idx = z - 3072;                 // 144 n-tiles x 48 k-tiles
    W = w_qkv; Wt = wqkvT; K = EMB; N = N3;
    n0 = (idx % 144) * 32; k0 = (idx / 144) * 32;
  } else {
    int idx = z - 9984;                 // 48 x 48
    W = w_proj; Wt = wprojT; K = EMB; N = EMB;
    n0 = (idx % 48) * 32; k0 = (idx / 48) * 32;
  }
  const int tx = tid & 31, ty = tid >> 5;   // (32,8)
#pragma unroll
  for (int r = 0; r < 4; ++r) {
    int k = ty + r * 8;
    t[k][tx] = W[(size_t)(k0 + k) * N + n0 + tx];
  }
  __syncthreads();
#pragma unroll
  for (int r = 0; r < 4; ++r) {
    int j = ty + r * 8;
    Wt[(size_t)(n0 + j) * K + k0 + tx] = f2bf(t[tx][j]);
  }
}

// ---------------- bf16 GEMM v8 (QKV): split-K=2, 128x128 tile, BK=64, single 32KB buffer ----------------
__global__ __launch_bounds__(256, 4) void k_gemm_v8(const short* __restrict__ A,
                                                    const short* __restrict__ Bt,
                                                    const float* __restrict__ bias,
                                                    short* __restrict__ C0,
                                                    short* __restrict__ C1,
                                                    int M, int N, int K) {
  __shared__ short lds[2][128 * 64];   // [A/B][row*64 + k], 32 KiB total
  const int tid = threadIdx.x;
  const int lane = tid & 63, wid = tid >> 6;
  const int wr = (wid >> 1) * 64, wc = (wid & 1) * 64;
  const int bn = blockIdx.x * 128, bm = blockIdx.y * 128;
  const int z = blockIdx.z;
  const int lr = lane & 15, lg = lane >> 4;
  const int swz = (lr & 7) << 4;

  const int srow = lane >> 3;                  // row within 8-row segment
  const int skc  = ((lane & 7) ^ srow) * 8;    // pre-swizzled global k offset

  f32x4 acc[4][4] = {};
  const int kh = K >> 1;
  const int k0 = z * kh;
  const int nk = kh >> 6;

  for (int t = 0; t < nk; ++t) {
    const int kt = k0 + (t << 6);
    __syncthreads();
#pragma unroll
    for (int it = 0; it < 4; ++it) {
      int seg = wid * 4 + it;
      int row = seg * 8 + srow;
      gload_lds16(A  + (size_t)(bm + row) * K + kt + skc, &lds[0][seg * 512]);
      gload_lds16(Bt + (size_t)(bn + row) * K + kt + skc, &lds[1][seg * 512]);
    }
    __syncthreads();
    const char* baseA = (const char*)&lds[0][0];
    const char* baseB = (const char*)&lds[1][0];
#pragma unroll
    for (int kk = 0; kk < 2; ++kk) {
      short8_t af[4], bfr[4];
#pragma unroll
      for (int m = 0; m < 4; ++m) {
        int row = wr + m * 16 + lr;
        af[m] = *(const short8_t*)(baseA + ((row * 128 + kk * 64 + lg * 16) ^ swz));
      }
#pragma unroll
      for (int n = 0; n < 4; ++n) {
        int row = wc + n * 16 + lr;
        bfr[n] = *(const short8_t*)(baseB + ((row * 128 + kk * 64 + lg * 16) ^ swz));
      }
#pragma unroll
      for (int m = 0; m < 4; ++m)
#pragma unroll
        for (int n = 0; n < 4; ++n)
          acc[m][n] = __builtin_amdgcn_mfma_f32_16x16x32_bf16(af[m], bfr[n], acc[m][n], 0, 0, 0);
    }
  }

  short* C = z ? C1 : C0;
#pragma unroll
  for (int m = 0; m < 4; ++m)
#pragma unroll
    for (int n = 0; n < 4; ++n) {
      int col = bn + wc + n * 16 + lr;
      float bv = z ? 0.f : bias[col];
#pragma unroll
      for (int r = 0; r < 4; ++r) {
        int row = bm + wr + m * 16 + lg * 4 + r;
        C[(size_t)row * N + col] = f2bf(acc[m][n][r] + bv);
      }
    }
}

// ---------------- bf16 GEMM v7 (proj): v6b schedule + XCD-cohort partition ----------------
template<bool OBF>
__global__ __launch_bounds__(256, 2) void k_gemm_v7(const short* __restrict__ A,
                                                    const short* __restrict__ Bt,
                                                    const float* __restrict__ bias,
                                                    void* __restrict__ Cv,
                                                    int M, int N, int K) {
  __shared__ short lds[2][2][128 * 64];
  const int tid = threadIdx.x;
  const int lane = tid & 63, wid = tid >> 6;
  const int wr = (wid >> 1) * 64, wc = (wid & 1) * 64;

  const int nbn = N >> 7;
  const int perbn = nbn >> 2;
  const int x = blockIdx.x & 7;
  const int s = blockIdx.x >> 3;
  const int bm = ((x >> 2) * 8 + (s & 7)) * 128;
  const int bn = ((x & 3) * perbn + (s >> 3)) * 128;

  const int lr = lane & 15, lg = lane >> 4;
  const int swz = (lr & 7) << 4;
  const int srow = lane >> 3;
  const int skc  = ((lane & 7) ^ srow) * 8;

  f32x4 acc[4][4] = {};
  const int nk = K >> 6;

#define GSTAGE(kt_, buf_)                                                          \
  {                                                                                \
    const int kt__ = (kt_);                                                        \
    _Pragma("unroll")                                                              \
    for (int it = 0; it < 4; ++it) {                                               \
      int seg = wid * 4 + it;                                                      \
      int row = seg * 8 + srow;                                                    \
      gload_lds16(A  + (size_t)(bm + row) * K + kt__ + skc, &lds[buf_][0][seg * 512]); \
      gload_lds16(Bt + (size_t)(bn + row) * K + kt__ + skc, &lds[buf_][1][seg * 512]); \
    }                                                                              \
  }

  GSTAGE(0, 0);
  if (nk > 1) {
    GSTAGE(64, 1);
    asm volatile("s_waitcnt vmcnt(8)" ::: "memory");
  } else {
    asm volatile("s_waitcnt vmcnt(0)" ::: "memory");
  }
  __builtin_amdgcn_s_barrier();

  int cur = 0;
  for (int t = 0; t < nk; ++t) {
    const char* baseA = (const char*)&lds[cur][0][0];
    const char* baseB = (const char*)&lds[cur][1][0];

    short8_t af0[4], bf0[4], af1[4], bf1[4];
#pragma unroll
    for (int m = 0; m < 4; ++m) {
      int rowA = wr + m * 16 + lr;
      int rowB = wc + m * 16 + lr;
      af0[m] = *(const short8_t*)(baseA + ((rowA * 128 + 0 * 64 + lg * 16) ^ swz));
      bf0[m] = *(const short8_t*)(baseB + ((rowB * 128 + 0 * 64 + lg * 16) ^ swz));
      af1[m] = *(const short8_t*)(baseA + ((rowA * 128 + 1 * 64 + lg * 16) ^ swz));
      bf1[m] = *(const short8_t*)(baseB + ((rowB * 128 + 1 * 64 + lg * 16) ^ swz));
    }

    __builtin_amdgcn_s_setprio(1);
#pragma unroll
    for (int m = 0; m < 4; ++m)
#pragma unroll
      for (int n = 0; n < 4; ++n)
        acc[m][n] = __builtin_amdgcn_mfma_f32_16x16x32_bf16(af0[m], bf0[n], acc[m][n], 0, 0, 0);
    __builtin_amdgcn_s_setprio(0);

    // rule-#18 fence: sched_barrier(0) right after inline-asm lgkmcnt(0)
    asm volatile("s_waitcnt lgkmcnt(0)" ::: "memory");
    __builtin_amdgcn_sched_barrier(0);
    __builtin_amdgcn_s_barrier();

    if (t + 2 < nk) GSTAGE((t + 2) << 6, cur);

    __builtin_amdgcn_s_setprio(1);
#pragma unroll
    for (int m = 0; m < 4; ++m)
#pragma unroll
      for (int n = 0; n < 4; ++n)
        acc[m][n] = __builtin_amdgcn_mfma_f32_16x16x32_bf16(af1[m], bf1[n], acc[m][n], 0, 0, 0);
    __builtin_amdgcn_s_setprio(0);

    if (t + 2 < nk) {
      asm volatile("s_waitcnt vmcnt(8)" ::: "memory");
    } else {
      asm volatile("s_waitcnt vmcnt(0)" ::: "memory");
    }
    __builtin_amdgcn_s_barrier();
    cur ^= 1;
  }
#undef GSTAGE

#pragma unroll
  for (int m = 0; m < 4; ++m)
#pragma unroll
    for (int n = 0; n < 4; ++n) {
      int col = bn + wc + n * 16 + lr;
      float bv = bias[col];
#pragma unroll
      for (int r = 0; r < 4; ++r) {
        int row = bm + wr + m * 16 + lg * 4 + r;
        float v = acc[m][n][r] + bv;
        if (OBF) ((short*)Cv)[(size_t)row * N + col] = f2bf(v);
        else     ((float*)Cv)[(size_t)row * N + col] = v;
      }
    }
}

// ---------------- fused RMSNorm + RoPE (q,k) + V transpose; sums split-K halves ----------------
__global__ __launch_bounds__(256) void k_post(const short* __restrict__ qkvA,
                                              const short* __restrict__ qkvB,
                                              const float* __restrict__ cosv,
                                              const float* __restrict__ sinv,
                                              const float* __restrict__ qw,
                                              const float* __restrict__ kw,
                                              short* __restrict__ qbo,
                                              short* __restrict__ kbo,
                                              short* __restrict__ vt) {
  __shared__ short ldsv[64 * 130];
  const int h = blockIdx.x, s0 = blockIdx.y * 64;
  const int t = threadIdx.x;
  const int r = t >> 2, j = t & 3;
  const int s = s0 + r;
  const size_t rowbase = (size_t)s * N3 + h * HD;
  const float SC2 = ATTN_SCALE * LOG2E;

  {
    const short* va = qkvA + rowbase + 2 * EMB + j * 32;
    const short* vb = qkvB + rowbase + 2 * EMB + j * 32;
#pragma unroll
    for (int i4 = 0; i4 < 4; ++i4) {
      short8_t xa = *(const short8_t*)(va + i4 * 8);
      short8_t xb = *(const short8_t*)(vb + i4 * 8);
      short8_t o8;
#pragma unroll
      for (int e = 0; e < 8; ++e) o8[e] = f2bf(bf2f(xa[e]) + bf2f(xb[e]));
      *(short8_t*)&ldsv[r * 130 + j * 32 + i4 * 8] = o8;
    }
  }

#pragma unroll
  for (int qk = 0; qk < 2; ++qk) {
    const short* pa = qkvA + rowbase + qk * EMB + j * 32;
    const short* pb = qkvB + rowbase + qk * EMB + j * 32;
    const float* w = qk ? kw : qw;
    float v[32];
#pragma unroll
    for (int i4 = 0; i4 < 4; ++i4) {
      short8_t xa = *(const short8_t*)(pa + i4 * 8);
      short8_t xb = *(const short8_t*)(pb + i4 * 8);
#pragma unroll
      for (int e = 0; e < 8; ++e) v[i4 * 8 + e] = bf2f(xa[e]) + bf2f(xb[e]);
    }
    float ss = 0.f;
#pragma unroll
    for (int i = 0; i < 32; ++i) ss += v[i] * v[i];
    ss += __shfl_xor(ss, 1);
    ss += __shfl_xor(ss, 2);
    float rsq = rsqrtf(ss * (1.0f / HD) + RMS_EPS);
    if (qk == 0) rsq *= SC2;
#pragma unroll
    for (int i = 0; i < 32; ++i) v[i] = v[i] * rsq * w[j * 32 + i];
    const float* cp = cosv + (size_t)s * 64 + (j & 1) * 32;
    const float* sp = sinv + (size_t)s * 64 + (j & 1) * 32;
    short out[32];
#pragma unroll
    for (int i = 0; i < 32; ++i) {
      float part = __shfl_xor(v[i], 2);
      float c = cp[i], sn = sp[i];
      float o = (j < 2) ? (v[i] * c - part * sn) : (v[i] * c + part * sn);
      out[i] = f2bf(o);
    }
    short* dst = (qk ? kbo : qbo) + ((size_t)h * S_LEN + s) * HD + j * 32;
#pragma unroll
    for (int i4 = 0; i4 < 4; ++i4) {
      short8_t o8;
#pragma unroll
      for (int e = 0; e < 8; ++e) o8[e] = out[i4 * 8 + e];
      *(short8_t*)(dst + i4 * 8) = o8;
    }
  }

  __syncthreads();
  const int sl = t & 63, wv = t >> 6;
#pragma unroll
  for (int it = 0; it < 32; ++it) {
    int d = it * 4 + wv;
    vt[((size_t)h * HD + d) * S_LEN + s0 + sl] = ldsv[sl * 130 + d];
  }
}

// ---------------- flash attention v6 (SPLIT=3): K half-tile layout, pre-scaled Q ----------------
__global__ __launch_bounds__(512, 2) void k_attn(const short* __restrict__ qb,
                                                 const short* __restrict__ kb,
                                                 const short* __restrict__ vt,
                                                 const int* __restrict__ cu, int nseg,
                                                 short* __restrict__ Opart,
                                                 float* __restrict__ mlpart) {
  __shared__ short ldsK[2][8192];
  __shared__ short ldsV[2][128 * 64];
  __shared__ short ldsP[8 * 16 * 64];

  // XCD-locality swizzle: wg = chunk + 72*member; 72%8==0 so all 8 members of a
  // (h,seg,p) chunk land on XCD chunk%8.
  const int wg = blockIdx.x;
  const int member = wg / 72;           // 0..7 (q-tile within segment)
  const int c = wg % 72;                // chunk = (h,seg,p)
  const int p = c % 3;
  const int hs = c / 3;                 // 0..23
  const int h = hs >> 1;
  const int qt = (hs & 1) * 8 + member;

  const int q0 = qt * 128;
  const int tid = threadIdx.x, l = tid & 63, w = tid >> 6;
  const int lr = l & 15, lg = l >> 4;

  const short* kb_h = kb + (size_t)h * S_LEN * HD;
  const short* vt_h = vt + (size_t)h * HD * S_LEN;

  const int qrow_sm = q0 + w * 16 + lr;
  int segq = 0;
  for (int i = 1; i <= nseg; ++i) if (qrow_sm >= cu[i]) segq = i;
  const int rs_s = (segq == 0) ? 0 : cu[segq];
  const int re_s = (segq < nseg) ? cu[segq + 1] : S_LEN;
  float m = -INFINITY, lsum = 0.f;

  int seg0 = 0, seg1 = 0;
  for (int i = 1; i <= nseg; ++i) {
    if (q0 >= cu[i]) seg0 = i;
    if (q0 + 127 >= cu[i]) seg1 = i;
  }
  const int ks = (seg0 == 0) ? 0 : cu[seg0];
  const int ke = (seg1 < nseg) ? cu[seg1 + 1] : S_LEN;
  const int kt0 = (ks >> 6) << 6;
  const int nt = (ke - kt0 + 63) >> 6;
  const int tpb = (nt + SPLIT - 1) / SPLIT;
  const int tb0 = p * tpb;
  const int tb1 = (tb0 + tpb < nt) ? tb0 + tpb : nt;

  const int vseg_row = l >> 3;

  short8_t qf[4];
  {
    int srow = q0 + w * 16 + lr;
    const short* qp = qb + ((size_t)h * S_LEN + srow) * HD;
#pragma unroll
    for (int kk = 0; kk < 4; ++kk)
      qf[kk] = *(const short8_t*)(qp + kk * 32 + lg * 8);
  }

  f32x4 cacc[8] = {};

#define STAGE(kt_, buf_)                                                          \
  {                                                                               \
    const int kt__ = (kt_);                                                       \
    _Pragma("unroll")                                                             \
    for (int it = 0; it < 2; ++it) {                                              \
      int s = w * 2 + it;                                                         \
      int half = s >> 3;                                                          \
      int krow = (s & 7) * 8 + (l >> 3);                                          \
      int kc = half * 64 + (((l & 7) ^ (l >> 3)) * 8);                            \
      gload_lds16(kb_h + (size_t)(kt__ + krow) * HD + kc, &ldsK[buf_][s * 512]);  \
      int drow = s * 8 + vseg_row;                                                \
      int sv = ((l & 7) ^ (drow & 7)) * 8;                                        \
      gload_lds16(vt_h + (size_t)drow * S_LEN + kt__ + sv, &ldsV[buf_][s * 512]); \
    }                                                                             \
  }

  if (tb0 < tb1)     STAGE(kt0 + tb0 * 64, 0);
  if (tb0 + 1 < tb1) {
    STAGE(kt0 + (tb0 + 1) * 64, 1);
    asm volatile("s_waitcnt vmcnt(4)" ::: "memory");
  } else {
    asm volatile("s_waitcnt vmcnt(0)" ::: "memory");
  }
  __builtin_amdgcn_s_barrier();

  int cur = 0;
  for (int ti = tb0; ti < tb1; ++ti) {
    const int kt = kt0 + ti * 64;
    const char* bK = (const char*)&ldsK[cur][0];
    const char* bV = (const char*)&ldsV[cur][0];

    f32x4 sacc[4] = {};
    __builtin_amdgcn_s_setprio(1);
#pragma unroll
    for (int n = 0; n < 4; ++n) {
#pragma unroll
      for (int kk = 0; kk < 4; ++kk) {
        int row = n * 16 + lr;
        int byte = (kk >> 1) * 8192 + row * 128 + (kk & 1) * 64 + lg * 16;
        byte ^= (lr & 7) << 4;
        short8_t kf = *(const short8_t*)(bK + byte);
        sacc[n] = __builtin_amdgcn_mfma_f32_16x16x32_bf16(kf, qf[kk], sacc[n], 0, 0, 0);
      }
    }
    __builtin_amdgcn_s_setprio(0);

    if (!__all((kt >= rs_s) && (kt + 64 <= re_s))) {
#pragma unroll
      for (int n = 0; n < 4; ++n) {
        int kbase = kt + n * 16 + lg * 4;
#pragma unroll
        for (int r = 0; r < 4; ++r) {
          int key = kbase + r;
          sacc[n][r] = (key >= rs_s && key < re_s) ? sacc[n][r] : -1e30f;
        }
      }
    }

    float tm = sacc[0][0];
#pragma unroll
    for (int n = 0; n < 4; ++n)
#pragma unroll
      for (int r = 0; r < 4; ++r) tm = fmaxf(tm, sacc[n][r]);
    tm = fmaxf(tm, __shfl_xor(tm, 16));
    tm = fmaxf(tm, __shfl_xor(tm, 32));

    if (!__all(tm <= m + DEFER_THR)) {
      float mn = fmaxf(m, tm);
      float alpha = exp2f(m - mn);
      m = mn;
      lsum *= alpha;
      float a[4];
#pragma unroll
      for (int r = 0; r < 4; ++r) a[r] = __shfl(alpha, lg * 4 + r);
#pragma unroll
      for (int n = 0; n < 8; ++n)
#pragma unroll
        for (int r = 0; r < 4; ++r) cacc[n][r] *= a[r];
    }

    float ls = 0.f;
#pragma unroll
    for (int n = 0; n < 4; ++n) {
      short4 p4;
      float p0 = exp2f(sacc[n][0] - m);
      float p1 = exp2f(sacc[n][1] - m);
      float p2 = exp2f(sacc[n][2] - m);
      float p3 = exp2f(sacc[n][3] - m);
      ls += (p0 + p1) + (p2 + p3);
      p4.x = f2bf(p0); p4.y = f2bf(p1); p4.z = f2bf(p2); p4.w = f2bf(p3);
      int byte = lr * 128 + (n * 16 + lg * 4) * 2;
      byte ^= (lr & 7) << 4;
      *(short4*)((char*)ldsP + w * 2048 + byte) = p4;
    }
    ls += __shfl_xor(ls, 16);
    ls += __shfl_xor(ls, 32);
    lsum += ls;

    __builtin_amdgcn_s_setprio(1);
#pragma unroll
    for (int kk = 0; kk < 2; ++kk) {
      int byteP = lr * 128 + (kk * 32 + lg * 8) * 2;
      byteP ^= (lr & 7) << 4;
      short8_t pf = *(const short8_t*)((const char*)ldsP + w * 2048 + byteP);
#pragma unroll
      for (int n = 0; n < 8; ++n) {
        int d = n * 16 + lr;
        int byteV = d * 128 + (kk * 32 + lg * 8) * 2;
        byteV ^= (d & 7) << 4;
        short8_t vf = *(const short8_t*)(bV + byteV);
        cacc[n] = __builtin_amdgcn_mfma_f32_16x16x32_bf16(pf, vf, cacc[n], 0, 0, 0);
      }
    }
    __builtin_amdgcn_s_setprio(0);

    __builtin_amdgcn_s_barrier();
    if (ti + 2 < tb1) {
      STAGE(kt0 + (ti + 2) * 64, cur);
      asm volatile("s_waitcnt vmcnt(4)" ::: "memory");
    } else {
      asm volatile("s_waitcnt vmcnt(0)" ::: "memory");
    }
    __builtin_amdgcn_s_barrier();
    cur ^= 1;
  }
#undef STAGE

  const int b = (h * 16 + qt) * SPLIT + p;
#pragma unroll
  for (int r = 0; r < 4; ++r) {
    int qrow = w * 16 + lg * 4 + r;
#pragma unroll
    for (int n = 0; n < 8; ++n)
      Opart[(size_t)b * 16384 + qrow * 128 + n * 16 + lr] = f2bf(cacc[n][r]);
  }
  if (lg == 0) {
    mlpart[(size_t)b * 256 + w * 16 + lr] = m;
    mlpart[(size_t)b * 256 + 128 + w * 16 + lr] = lsum;
  }
}

// ---------------- combine split-K partials -> ctx bf16 (log2-domain m) ----------------
__global__ __launch_bounds__(512) void k_combine(const short* __restrict__ Opart,
                                                 const float* __restrict__ ml,
                                                 short* __restrict__ ctx) {
  const int h = blockIdx.x, qt = blockIdx.y, t = threadIdx.x;
  const int r = t >> 2, j = t & 3;
  const int b0 = (h * 16 + qt) * SPLIT;

  float mp[SPLIT], lp[SPLIT], wp[SPLIT];
  float M = -INFINITY;
#pragma unroll
  for (int p = 0; p < SPLIT; ++p) {
    mp[p] = ml[(size_t)(b0 + p) * 256 + r];
    lp[p] = ml[(size_t)(b0 + p) * 256 + 128 + r];
    M = fmaxf(M, mp[p]);
  }
  float L = 0.f;
#pragma unroll
  for (int p = 0; p < SPLIT; ++p) {
    wp[p] = exp2f(mp[p] - M);
    L += lp[p] * wp[p];
  }
  const float inv = 1.0f / L;

  float acc[32];
#pragma unroll
  for (int i = 0; i < 32; ++i) acc[i] = 0.f;
#pragma unroll
  for (int p = 0; p < SPLIT; ++p) {
    const short* src = Opart + (size_t)(b0 + p) * 16384 + r * 128 + j * 32;
#pragma unroll
    for (int i4 = 0; i4 < 4; ++i4) {
      short8_t v = *(const short8_t*)(src + i4 * 8);
#pragma unroll
      for (int e = 0; e < 8; ++e) acc[i4 * 8 + e] += wp[p] * bf2f(v[e]);
    }
  }

  short* dst = ctx + (size_t)(qt * 128 + r) * EMB + h * HD + j * 32;
#pragma unroll
  for (int i4 = 0; i4 < 4; ++i4) {
    short8_t o8;
#pragma unroll
    for (int e = 0; e < 8; ++e) o8[e] = f2bf(acc[i4 * 8 + e] * inv);
    *(short8_t*)(dst + i4 * 8) = o8;
  }
}

extern "C" void kernel_launch(void* const* d_in, const int* in_sizes, int n_in,
                              void* d_out, int out_size, void* d_ws, size_t ws_size,
                              hipStream_t stream) {
  const float* x      = (const float*)d_in[0];
  const int*   cu     = (const int*)d_in[1];
  const float* cosv   = (const float*)d_in[2];
  const float* sinv   = (const float*)d_in[3];
  const float* w_qkv  = (const float*)d_in[4];
  const float* b_qkv  = (const float*)d_in[5];
  const float* q_norm = (const float*)d_in[6];
  const float* k_norm = (const float*)d_in[7];
  const float* w_proj = (const float*)d_in[8];
  const float* b_proj = (const float*)d_in[9];
  const int nseg = in_sizes[1] - 1;

  char* ws = (char*)d_ws;
  short* xb     = (short*)(ws);                    //  6,291,456 B (dead after QKV GEMM)
  short* wqkvT  = (short*)(ws + 6291456);          // 14,155,776 B
  short* wprojT = (short*)(ws + 20447232);         //  4,718,592 B
  short* qkvA   = (short*)(ws + 25165824);         // 18,874,368 B (dead after k_post)
  short* qb     = (short*)(ws + 44040192);         //  6,291,456 B
  short* kb     = (short*)(ws + 50331648);         //  6,291,456 B
  short* vt     = (short*)(ws + 56623104);         //  6,291,456 B
  short* ctxb   = (short*)(ws + 62914560);         //  6,291,456 B
  short* qkvB   = (short*)(ws + 69206016);         // 18,874,368 B (end 88,080,384)
  short* Opart  = qkvA;                            // reuse: 576*16384*2 = 18,874,368 B (exact)
  float* mlpart = (float*)ws;                      // reuse xb: 576*256*4 = 589,824 B

  k_prep<<<12288, 256, 0, stream>>>(x, w_qkv, w_proj, xb, wqkvT, wprojT);
  k_gemm_v8<<<dim3(N3 / 128, S_LEN / 128, 2), 256, 0, stream>>>(xb, wqkvT, b_qkv, qkvA, qkvB, S_LEN, N3, EMB);
  k_post<<<dim3(NH, S_LEN / 64), 256, 0, stream>>>(qkvA, qkvB, cosv, sinv, q_norm, k_norm, qb, kb, vt);
  k_attn<<<dim3(NH * 16 * SPLIT), 512, 0, stream>>>(qb, kb, vt, cu, nseg, Opart, mlpart);
  k_combine<<<dim3(NH, S_LEN / 128), 512, 0, stream>>>(Opart, mlpart, ctxb);
  k_gemm_v7<false><<<dim3((EMB / 128) * (S_LEN / 128)), 256, 0, stream>>>(ctxb, wprojT, b_proj, (float*)d_out, S_LEN, EMB, EMB);
}

// Round 18
// 127.996 us; speedup vs baseline: 1.0657x; 1.0423x over previous
//
#include <hip/hip_runtime.h>
#include <hip/hip_bf16.h>
#include <stdint.h>

#define S_LEN 2048
#define EMB   1536
#define NH    12
#define HD    128
#define N3    4608
#define RMS_EPS 1e-5f
#define ATTN_SCALE 0.08838834764831845f  // 1/sqrt(128)
#define SPLIT 3
#define LOG2E 1.44269504088896f
#define DEFER_THR 11.5416f   // 8 * log2(e)

typedef short short8_t __attribute__((ext_vector_type(8)));
typedef float f32x4    __attribute__((ext_vector_type(4)));

typedef __attribute__((address_space(1))) const void g1_void;
typedef __attribute__((address_space(3))) void l3_void;

__device__ __forceinline__ void gload_lds16(const void* g, void* l) {
  __builtin_amdgcn_global_load_lds((g1_void*)g, (l3_void*)l, 16, 0, 0);
}

__device__ __forceinline__ short f2bf(float f) {
  union { float f; unsigned u; } v; v.f = f;
  unsigned r = (v.u + 0x7FFFu + ((v.u >> 16) & 1u)) >> 16;
  return (short)(r & 0xFFFFu);
}
__device__ __forceinline__ float bf2f(short s) {
  union { unsigned u; float f; } v; v.u = ((unsigned)(unsigned short)s) << 16;
  return v.f;
}

// ---------------- merged prep: x->bf16 cvt + both weight transposes (1 dispatch) ----------------
__global__ __launch_bounds__(256) void k_prep(const float* __restrict__ x,
                                              const float* __restrict__ w_qkv,
                                              const float* __restrict__ w_proj,
                                              short* __restrict__ xb,
                                              short* __restrict__ wqkvT,
                                              short* __restrict__ wprojT) {
  const int z = blockIdx.x, tid = threadIdx.x;
  if (z < 3072) {
    int i = z * 1024 + tid * 4;
    float4 v = *(const float4*)(x + i);
    short4 o;
    o.x = f2bf(v.x); o.y = f2bf(v.y); o.z = f2bf(v.z); o.w = f2bf(v.w);
    *(short4*)(xb + i) = o;
    return;
  }
  __shared__ float t[32][33];
  const float* W; short* Wt; int K, N, n0, k0;
  if (z < 9984) {
    int idx = z - 3072;                 // 144 n-tiles x 48 k-tiles
    W = w_qkv; Wt = wqkvT; K = EMB; N = N3;
    n0 = (idx % 144) * 32; k0 = (idx / 144) * 32;
  } else {
    int idx = z - 9984;                 // 48 x 48
    W = w_proj; Wt = wprojT; K = EMB; N = EMB;
    n0 = (idx % 48) * 32; k0 = (idx / 48) * 32;
  }
  const int tx = tid & 31, ty = tid >> 5;   // (32,8)
#pragma unroll
  for (int r = 0; r < 4; ++r) {
    int k = ty + r * 8;
    t[k][tx] = W[(size_t)(k0 + k) * N + n0 + tx];
  }
  __syncthreads();
#pragma unroll
  for (int r = 0; r < 4; ++r) {
    int j = ty + r * 8;
    Wt[(size_t)(n0 + j) * K + k0 + tx] = f2bf(t[tx][j]);
  }
}

// ---------------- bf16 GEMM v7: v6b kk-interleaved schedule + XCD-cohort partition ----------------
template<bool OBF>
__global__ __launch_bounds__(256, 2) void k_gemm_v7(const short* __restrict__ A,
                                                    const short* __restrict__ Bt,
                                                    const float* __restrict__ bias,
                                                    void* __restrict__ Cv,
                                                    int M, int N, int K) {
  __shared__ short lds[2][2][128 * 64];   // [buf][A/B][row*64+k], 64 KiB
  const int tid = threadIdx.x;
  const int lane = tid & 63, wid = tid >> 6;
  const int wr = (wid >> 1) * 64, wc = (wid & 1) * 64;

  const int nbn = N >> 7;
  const int perbn = nbn >> 2;
  const int x = blockIdx.x & 7;
  const int s = blockIdx.x >> 3;
  const int bm = ((x >> 2) * 8 + (s & 7)) * 128;
  const int bn = ((x & 3) * perbn + (s >> 3)) * 128;

  const int lr = lane & 15, lg = lane >> 4;
  const int swz = (lr & 7) << 4;
  const int srow = lane >> 3;
  const int skc  = ((lane & 7) ^ srow) * 8;

  f32x4 acc[4][4] = {};
  const int nk = K >> 6;

#define GSTAGE(kt_, buf_)                                                          \
  {                                                                                \
    const int kt__ = (kt_);                                                        \
    _Pragma("unroll")                                                              \
    for (int it = 0; it < 4; ++it) {                                               \
      int seg = wid * 4 + it;                                                      \
      int row = seg * 8 + srow;                                                    \
      gload_lds16(A  + (size_t)(bm + row) * K + kt__ + skc, &lds[buf_][0][seg * 512]); \
      gload_lds16(Bt + (size_t)(bn + row) * K + kt__ + skc, &lds[buf_][1][seg * 512]); \
    }                                                                              \
  }

  GSTAGE(0, 0);
  if (nk > 1) {
    GSTAGE(64, 1);
    asm volatile("s_waitcnt vmcnt(8)" ::: "memory");
  } else {
    asm volatile("s_waitcnt vmcnt(0)" ::: "memory");
  }
  __builtin_amdgcn_s_barrier();

  int cur = 0;
  for (int t = 0; t < nk; ++t) {
    const char* baseA = (const char*)&lds[cur][0][0];
    const char* baseB = (const char*)&lds[cur][1][0];

    short8_t af0[4], bf0[4], af1[4], bf1[4];
#pragma unroll
    for (int m = 0; m < 4; ++m) {
      int rowA = wr + m * 16 + lr;
      int rowB = wc + m * 16 + lr;
      af0[m] = *(const short8_t*)(baseA + ((rowA * 128 + 0 * 64 + lg * 16) ^ swz));
      bf0[m] = *(const short8_t*)(baseB + ((rowB * 128 + 0 * 64 + lg * 16) ^ swz));
      af1[m] = *(const short8_t*)(baseA + ((rowA * 128 + 1 * 64 + lg * 16) ^ swz));
      bf1[m] = *(const short8_t*)(baseB + ((rowB * 128 + 1 * 64 + lg * 16) ^ swz));
    }

    __builtin_amdgcn_s_setprio(1);
#pragma unroll
    for (int m = 0; m < 4; ++m)
#pragma unroll
      for (int n = 0; n < 4; ++n)
        acc[m][n] = __builtin_amdgcn_mfma_f32_16x16x32_bf16(af0[m], bf0[n], acc[m][n], 0, 0, 0);
    __builtin_amdgcn_s_setprio(0);

    // rule-#18 fence: sched_barrier(0) right after inline-asm lgkmcnt(0)
    asm volatile("s_waitcnt lgkmcnt(0)" ::: "memory");
    __builtin_amdgcn_sched_barrier(0);
    __builtin_amdgcn_s_barrier();

    if (t + 2 < nk) GSTAGE((t + 2) << 6, cur);

    __builtin_amdgcn_s_setprio(1);
#pragma unroll
    for (int m = 0; m < 4; ++m)
#pragma unroll
      for (int n = 0; n < 4; ++n)
        acc[m][n] = __builtin_amdgcn_mfma_f32_16x16x32_bf16(af1[m], bf1[n], acc[m][n], 0, 0, 0);
    __builtin_amdgcn_s_setprio(0);

    if (t + 2 < nk) {
      asm volatile("s_waitcnt vmcnt(8)" ::: "memory");
    } else {
      asm volatile("s_waitcnt vmcnt(0)" ::: "memory");
    }
    __builtin_amdgcn_s_barrier();
    cur ^= 1;
  }
#undef GSTAGE

#pragma unroll
  for (int m = 0; m < 4; ++m)
#pragma unroll
    for (int n = 0; n < 4; ++n) {
      int col = bn + wc + n * 16 + lr;
      float bv = bias[col];
#pragma unroll
      for (int r = 0; r < 4; ++r) {
        int row = bm + wr + m * 16 + lg * 4 + r;
        float v = acc[m][n][r] + bv;
        if (OBF) ((short*)Cv)[(size_t)row * N + col] = f2bf(v);
        else     ((float*)Cv)[(size_t)row * N + col] = v;
      }
    }
}

// ---------------- fused RMSNorm + RoPE (q,k) + V transpose; q pre-scaled by SC2 ----------------
__global__ __launch_bounds__(256) void k_post(const short* __restrict__ qkv,
                                              const float* __restrict__ cosv,
                                              const float* __restrict__ sinv,
                                              const float* __restrict__ qw,
                                              const float* __restrict__ kw,
                                              short* __restrict__ qbo,
                                              short* __restrict__ kbo,
                                              short* __restrict__ vt) {
  __shared__ short ldsv[64 * 130];
  const int h = blockIdx.x, s0 = blockIdx.y * 64;
  const int t = threadIdx.x;
  const int r = t >> 2, j = t & 3;
  const int s = s0 + r;
  const size_t rowbase = (size_t)s * N3 + h * HD;
  const float SC2 = ATTN_SCALE * LOG2E;

  {
    const short* vp = qkv + rowbase + 2 * EMB + j * 32;
#pragma unroll
    for (int i4 = 0; i4 < 4; ++i4)
      *(short8_t*)&ldsv[r * 130 + j * 32 + i4 * 8] = *(const short8_t*)(vp + i4 * 8);
  }

#pragma unroll
  for (int qk = 0; qk < 2; ++qk) {
    const short* p = qkv + rowbase + qk * EMB + j * 32;
    const float* w = qk ? kw : qw;
    float v[32];
#pragma unroll
    for (int i4 = 0; i4 < 4; ++i4) {
      short8_t xv = *(const short8_t*)(p + i4 * 8);
#pragma unroll
      for (int e = 0; e < 8; ++e) v[i4 * 8 + e] = bf2f(xv[e]);
    }
    float ss = 0.f;
#pragma unroll
    for (int i = 0; i < 32; ++i) ss += v[i] * v[i];
    ss += __shfl_xor(ss, 1);
    ss += __shfl_xor(ss, 2);
    float rsq = rsqrtf(ss * (1.0f / HD) + RMS_EPS);
    if (qk == 0) rsq *= SC2;   // bake attention scale + log2e into q
#pragma unroll
    for (int i = 0; i < 32; ++i) v[i] = v[i] * rsq * w[j * 32 + i];
    const float* cp = cosv + (size_t)s * 64 + (j & 1) * 32;
    const float* sp = sinv + (size_t)s * 64 + (j & 1) * 32;
    short out[32];
#pragma unroll
    for (int i = 0; i < 32; ++i) {
      float part = __shfl_xor(v[i], 2);
      float c = cp[i], sn = sp[i];
      float o = (j < 2) ? (v[i] * c - part * sn) : (v[i] * c + part * sn);
      out[i] = f2bf(o);
    }
    short* dst = (qk ? kbo : qbo) + ((size_t)h * S_LEN + s) * HD + j * 32;
#pragma unroll
    for (int i4 = 0; i4 < 4; ++i4) {
      short8_t o8;
#pragma unroll
      for (int e = 0; e < 8; ++e) o8[e] = out[i4 * 8 + e];
      *(short8_t*)(dst + i4 * 8) = o8;
    }
  }

  __syncthreads();
  const int sl = t & 63, wv = t >> 6;
#pragma unroll
  for (int it = 0; it < 32; ++it) {
    int d = it * 4 + wv;
    vt[((size_t)h * HD + d) * S_LEN + s0 + sl] = ldsv[sl * 130 + d];
  }
}

// ---------------- flash attention v6 (SPLIT=3): K half-tile layout, pre-scaled Q ----------------
__global__ __launch_bounds__(512, 2) void k_attn(const short* __restrict__ qb,
                                                 const short* __restrict__ kb,
                                                 const short* __restrict__ vt,
                                                 const int* __restrict__ cu, int nseg,
                                                 short* __restrict__ Opart,
                                                 float* __restrict__ mlpart) {
  __shared__ short ldsK[2][8192];
  __shared__ short ldsV[2][128 * 64];
  __shared__ short ldsP[8 * 16 * 64];

  // XCD-locality swizzle: wg = chunk + 72*member; 72%8==0 so all 8 members of a
  // (h,seg,p) chunk land on XCD chunk%8.
  const int wg = blockIdx.x;
  const int member = wg / 72;
  const int c = wg % 72;
  const int p = c % 3;
  const int hs = c / 3;
  const int h = hs >> 1;
  const int qt = (hs & 1) * 8 + member;

  const int q0 = qt * 128;
  const int tid = threadIdx.x, l = tid & 63, w = tid >> 6;
  const int lr = l & 15, lg = l >> 4;

  const short* kb_h = kb + (size_t)h * S_LEN * HD;
  const short* vt_h = vt + (size_t)h * HD * S_LEN;

  const int qrow_sm = q0 + w * 16 + lr;
  int segq = 0;
  for (int i = 1; i <= nseg; ++i) if (qrow_sm >= cu[i]) segq = i;
  const int rs_s = (segq == 0) ? 0 : cu[segq];
  const int re_s = (segq < nseg) ? cu[segq + 1] : S_LEN;
  float m = -INFINITY, lsum = 0.f;

  int seg0 = 0, seg1 = 0;
  for (int i = 1; i <= nseg; ++i) {
    if (q0 >= cu[i]) seg0 = i;
    if (q0 + 127 >= cu[i]) seg1 = i;
  }
  const int ks = (seg0 == 0) ? 0 : cu[seg0];
  const int ke = (seg1 < nseg) ? cu[seg1 + 1] : S_LEN;
  const int kt0 = (ks >> 6) << 6;
  const int nt = (ke - kt0 + 63) >> 6;
  const int tpb = (nt + SPLIT - 1) / SPLIT;
  const int tb0 = p * tpb;
  const int tb1 = (tb0 + tpb < nt) ? tb0 + tpb : nt;

  const int vseg_row = l >> 3;

  short8_t qf[4];
  {
    int srow = q0 + w * 16 + lr;
    const short* qp = qb + ((size_t)h * S_LEN + srow) * HD;
#pragma unroll
    for (int kk = 0; kk < 4; ++kk)
      qf[kk] = *(const short8_t*)(qp + kk * 32 + lg * 8);
  }

  f32x4 cacc[8] = {};

#define STAGE(kt_, buf_)                                                          \
  {                                                                               \
    const int kt__ = (kt_);                                                       \
    _Pragma("unroll")                                                             \
    for (int it = 0; it < 2; ++it) {                                              \
      int s = w * 2 + it;                                                         \
      int half = s >> 3;                                                          \
      int krow = (s & 7) * 8 + (l >> 3);                                          \
      int kc = half * 64 + (((l & 7) ^ (l >> 3)) * 8);                            \
      gload_lds16(kb_h + (size_t)(kt__ + krow) * HD + kc, &ldsK[buf_][s * 512]);  \
      int drow = s * 8 + vseg_row;                                                \
      int sv = ((l & 7) ^ (drow & 7)) * 8;                                        \
      gload_lds16(vt_h + (size_t)drow * S_LEN + kt__ + sv, &ldsV[buf_][s * 512]); \
    }                                                                             \
  }

  if (tb0 < tb1)     STAGE(kt0 + tb0 * 64, 0);
  if (tb0 + 1 < tb1) {
    STAGE(kt0 + (tb0 + 1) * 64, 1);
    asm volatile("s_waitcnt vmcnt(4)" ::: "memory");
  } else {
    asm volatile("s_waitcnt vmcnt(0)" ::: "memory");
  }
  __builtin_amdgcn_s_barrier();

  int cur = 0;
  for (int ti = tb0; ti < tb1; ++ti) {
    const int kt = kt0 + ti * 64;
    const char* bK = (const char*)&ldsK[cur][0];
    const char* bV = (const char*)&ldsV[cur][0];

    f32x4 sacc[4] = {};
    __builtin_amdgcn_s_setprio(1);
#pragma unroll
    for (int n = 0; n < 4; ++n) {
#pragma unroll
      for (int kk = 0; kk < 4; ++kk) {
        int row = n * 16 + lr;
        int byte = (kk >> 1) * 8192 + row * 128 + (kk & 1) * 64 + lg * 16;
        byte ^= (lr & 7) << 4;
        short8_t kf = *(const short8_t*)(bK + byte);
        sacc[n] = __builtin_amdgcn_mfma_f32_16x16x32_bf16(kf, qf[kk], sacc[n], 0, 0, 0);
      }
    }
    __builtin_amdgcn_s_setprio(0);

    if (!__all((kt >= rs_s) && (kt + 64 <= re_s))) {
#pragma unroll
      for (int n = 0; n < 4; ++n) {
        int kbase = kt + n * 16 + lg * 4;
#pragma unroll
        for (int r = 0; r < 4; ++r) {
          int key = kbase + r;
          sacc[n][r] = (key >= rs_s && key < re_s) ? sacc[n][r] : -1e30f;
        }
      }
    }

    float tm = sacc[0][0];
#pragma unroll
    for (int n = 0; n < 4; ++n)
#pragma unroll
      for (int r = 0; r < 4; ++r) tm = fmaxf(tm, sacc[n][r]);
    tm = fmaxf(tm, __shfl_xor(tm, 16));
    tm = fmaxf(tm, __shfl_xor(tm, 32));

    if (!__all(tm <= m + DEFER_THR)) {
      float mn = fmaxf(m, tm);
      float alpha = exp2f(m - mn);
      m = mn;
      lsum *= alpha;
      float a[4];
#pragma unroll
      for (int r = 0; r < 4; ++r) a[r] = __shfl(alpha, lg * 4 + r);
#pragma unroll
      for (int n = 0; n < 8; ++n)
#pragma unroll
        for (int r = 0; r < 4; ++r) cacc[n][r] *= a[r];
    }

    float ls = 0.f;
#pragma unroll
    for (int n = 0; n < 4; ++n) {
      short4 p4;
      float p0 = exp2f(sacc[n][0] - m);
      float p1 = exp2f(sacc[n][1] - m);
      float p2 = exp2f(sacc[n][2] - m);
      float p3 = exp2f(sacc[n][3] - m);
      ls += (p0 + p1) + (p2 + p3);
      p4.x = f2bf(p0); p4.y = f2bf(p1); p4.z = f2bf(p2); p4.w = f2bf(p3);
      int byte = lr * 128 + (n * 16 + lg * 4) * 2;
      byte ^= (lr & 7) << 4;
      *(short4*)((char*)ldsP + w * 2048 + byte) = p4;
    }
    ls += __shfl_xor(ls, 16);
    ls += __shfl_xor(ls, 32);
    lsum += ls;

    __builtin_amdgcn_s_setprio(1);
#pragma unroll
    for (int kk = 0; kk < 2; ++kk) {
      int byteP = lr * 128 + (kk * 32 + lg * 8) * 2;
      byteP ^= (lr & 7) << 4;
      short8_t pf = *(const short8_t*)((const char*)ldsP + w * 2048 + byteP);
#pragma unroll
      for (int n = 0; n < 8; ++n) {
        int d = n * 16 + lr;
        int byteV = d * 128 + (kk * 32 + lg * 8) * 2;
        byteV ^= (d & 7) << 4;
        short8_t vf = *(const short8_t*)(bV + byteV);
        cacc[n] = __builtin_amdgcn_mfma_f32_16x16x32_bf16(pf, vf, cacc[n], 0, 0, 0);
      }
    }
    __builtin_amdgcn_s_setprio(0);

    __builtin_amdgcn_s_barrier();
    if (ti + 2 < tb1) {
      STAGE(kt0 + (ti + 2) * 64, cur);
      asm volatile("s_waitcnt vmcnt(4)" ::: "memory");
    } else {
      asm volatile("s_waitcnt vmcnt(0)" ::: "memory");
    }
    __builtin_amdgcn_s_barrier();
    cur ^= 1;
  }
#undef STAGE

  const int b = (h * 16 + qt) * SPLIT + p;
#pragma unroll
  for (int r = 0; r < 4; ++r) {
    int qrow = w * 16 + lg * 4 + r;
#pragma unroll
    for (int n = 0; n < 8; ++n)
      Opart[(size_t)b * 16384 + qrow * 128 + n * 16 + lr] = f2bf(cacc[n][r]);
  }
  if (lg == 0) {
    mlpart[(size_t)b * 256 + w * 16 + lr] = m;
    mlpart[(size_t)b * 256 + 128 + w * 16 + lr] = lsum;
  }
}

// ---------------- combine split-K partials -> ctx bf16 (log2-domain m) ----------------
__global__ __launch_bounds__(512) void k_combine(const short* __restrict__ Opart,
                                                 const float* __restrict__ ml,
                                                 short* __restrict__ ctx) {
  const int h = blockIdx.x, qt = blockIdx.y, t = threadIdx.x;
  const int r = t >> 2, j = t & 3;
  const int b0 = (h * 16 + qt) * SPLIT;

  float mp[SPLIT], lp[SPLIT], wp[SPLIT];
  float M = -INFINITY;
#pragma unroll
  for (int p = 0; p < SPLIT; ++p) {
    mp[p] = ml[(size_t)(b0 + p) * 256 + r];
    lp[p] = ml[(size_t)(b0 + p) * 256 + 128 + r];
    M = fmaxf(M, mp[p]);
  }
  float L = 0.f;
#pragma unroll
  for (int p = 0; p < SPLIT; ++p) {
    wp[p] = exp2f(mp[p] - M);
    L += lp[p] * wp[p];
  }
  const float inv = 1.0f / L;

  float acc[32];
#pragma unroll
  for (int i = 0; i < 32; ++i) acc[i] = 0.f;
#pragma unroll
  for (int p = 0; p < SPLIT; ++p) {
    const short* src = Opart + (size_t)(b0 + p) * 16384 + r * 128 + j * 32;
#pragma unroll
    for (int i4 = 0; i4 < 4; ++i4) {
      short8_t v = *(const short8_t*)(src + i4 * 8);
#pragma unroll
      for (int e = 0; e < 8; ++e) acc[i4 * 8 + e] += wp[p] * bf2f(v[e]);
    }
  }

  short* dst = ctx + (size_t)(qt * 128 + r) * EMB + h * HD + j * 32;
#pragma unroll
  for (int i4 = 0; i4 < 4; ++i4) {
    short8_t o8;
#pragma unroll
    for (int e = 0; e < 8; ++e) o8[e] = f2bf(acc[i4 * 8 + e] * inv);
    *(short8_t*)(dst + i4 * 8) = o8;
  }
}

extern "C" void kernel_launch(void* const* d_in, const int* in_sizes, int n_in,
                              void* d_out, int out_size, void* d_ws, size_t ws_size,
                              hipStream_t stream) {
  const float* x      = (const float*)d_in[0];
  const int*   cu     = (const int*)d_in[1];
  const float* cosv   = (const float*)d_in[2];
  const float* sinv   = (const float*)d_in[3];
  const float* w_qkv  = (const float*)d_in[4];
  const float* b_qkv  = (const float*)d_in[5];
  const float* q_norm = (const float*)d_in[6];
  const float* k_norm = (const float*)d_in[7];
  const float* w_proj = (const float*)d_in[8];
  const float* b_proj = (const float*)d_in[9];
  const int nseg = in_sizes[1] - 1;

  char* ws = (char*)d_ws;
  short* xb     = (short*)(ws);                    //  6,291,456 B (dead after QKV GEMM)
  short* wqkvT  = (short*)(ws + 6291456);          // 14,155,776 B
  short* wprojT = (short*)(ws + 20447232);         //  4,718,592 B
  short* qkv16  = (short*)(ws + 25165824);         // 18,874,368 B (dead after k_post)
  short* qb     = (short*)(ws + 44040192);         //  6,291,456 B
  short* kb     = (short*)(ws + 50331648);         //  6,291,456 B
  short* vt     = (short*)(ws + 56623104);         //  6,291,456 B
  short* ctxb   = (short*)(ws + 62914560);         //  6,291,456 B (end 69,206,016)
  short* Opart  = qkv16;                           // reuse: 576*16384*2 = 18,874,368 B (exact)
  float* mlpart = (float*)ws;                      // reuse xb: 576*256*4 = 589,824 B

  k_prep<<<12288, 256, 0, stream>>>(x, w_qkv, w_proj, xb, wqkvT, wprojT);
  k_gemm_v7<true><<<dim3((N3 / 128) * (S_LEN / 128)), 256, 0, stream>>>(xb, wqkvT, b_qkv, qkv16, S_LEN, N3, EMB);
  k_post<<<dim3(NH, S_LEN / 64), 256, 0, stream>>>(qkv16, cosv, sinv, q_norm, k_norm, qb, kb, vt);
  k_attn<<<dim3(NH * 16 * SPLIT), 512, 0, stream>>>(qb, kb, vt, cu, nseg, Opart, mlpart);
  k_combine<<<dim3(NH, S_LEN / 128), 512, 0, stream>>>(Opart, mlpart, ctxb);
  k_gemm_v7<false><<<dim3((EMB / 128) * (S_LEN / 128)), 256, 0, stream>>>(ctxb, wprojT, b_proj, (float*)d_out, S_LEN, EMB, EMB);
}